// Round 6
// baseline (96.877 us; speedup 1.0000x reference)
//
#include <hip/hip_runtime.h>
#include <math.h>

#define POOL 7
#define FH 50
#define FW 50
#define FC 1024
#define FC4 (FC / 4)      // 256 float4 groups per spatial cell
#define CHUNKS 4          // channel chunks; 64 float4 (256 ch) per chunk
#define F4C 64            // float4 per cell per chunk (one wave-wide load)

typedef float vf4 __attribute__((ext_vector_type(4)));

static __device__ __forceinline__ vf4 vmax4(vf4 a, vf4 b) {
    vf4 r;
    r.x = fmaxf(a.x, b.x);
    r.y = fmaxf(a.y, b.y);
    r.z = fmaxf(a.z, b.z);
    r.w = fmaxf(a.w, b.w);
    return r;
}

// XCD-pinned, latency-optimized RoI max-pool.
// chunk = b & 3 pins each XCD (round-robin b%8) to one 2.56 MB channel slice
// (L2-resident). 4 waves/block, one (roi,bin) per wave. Inner loop unrolled
// 2 rows x 2 cols -> 4 independent 1KB loads in flight per iteration.
__global__ __launch_bounds__(256) void roipool_kernel(
    const float* __restrict__ fm,     // [FH, FW, FC]
    const float* __restrict__ rois,   // [N, 4] (y1, x1, y2, x2) normalized
    float* __restrict__ out,          // [N, 7, 7, FC]
    int nbins)
{
    const int b     = blockIdx.x;
    const int chunk = b & (CHUNKS - 1);       // pinned per XCD
    const int wave  = threadIdx.x >> 6;
    const int lane  = threadIdx.x & 63;
    const int gid   = (b >> 2) * 4 + wave;    // bin id: n*49 + i*7 + j
    if (gid >= nbins) return;

    const int n  = gid / 49;
    const int ij = gid - n * 49;
    const int i  = ij / 7;
    const int j  = ij - i * 7;

    // ROI corners: truncating float->int cast, matching jnp astype(int32)
    const float4 roi = reinterpret_cast<const float4*>(rois)[n];
    const int h0 = (int)((float)FH * roi.x);
    const int w0 = (int)((float)FW * roi.y);
    const int h1 = (int)((float)FH * roi.z);
    const int w1 = (int)((float)FW * roi.w);
    const int rh = h1 - h0;
    const int rw = w1 - w0;
    const int hstep = rh / POOL;
    const int wstep = rw / POOL;

    // bin bounds (region-relative) + empty-bin adjustment
    int sh = i * hstep;
    int eh = (i < POOL - 1) ? (i + 1) * hstep : rh;
    if (sh == eh) { if (eh < rh) eh += 1; else sh -= 1; }
    int sw = j * wstep;
    int ew = (j < POOL - 1) ? (j + 1) * wstep : rw;
    if (sw == ew) { if (ew < rw) ew += 1; else sw -= 1; }

    // global row/col range, clamped to the feature map (mask semantics)
    const int r0 = max(0, h0 + sh);
    const int r1 = min(FH, h0 + eh);
    const int c0 = max(0, w0 + sw);
    const int c1 = min(FW, w0 + ew);

    // this wave's float4 index within a cell for its pinned channel chunk
    const int f4 = chunk * F4C + lane;        // [0, 256)

    vf4 acc = {-INFINITY, -INFINITY, -INFINITY, -INFINITY};

    const vf4* fm4 = reinterpret_cast<const vf4*>(fm);
    const size_t rowstride = (size_t)FW * FC4;

    int r = r0;
    for (; r + 1 < r1; r += 2) {
        const vf4* rp0 = fm4 + (size_t)r * rowstride + f4;
        const vf4* rp1 = rp0 + rowstride;
        int c = c0;
        for (; c + 1 < c1; c += 2) {
            vf4 a0 = rp0[(size_t)c * FC4];
            vf4 a1 = rp0[(size_t)(c + 1) * FC4];
            vf4 b0 = rp1[(size_t)c * FC4];
            vf4 b1 = rp1[(size_t)(c + 1) * FC4];
            acc = vmax4(acc, vmax4(vmax4(a0, a1), vmax4(b0, b1)));
        }
        if (c < c1) {
            vf4 a0 = rp0[(size_t)c * FC4];
            vf4 b0 = rp1[(size_t)c * FC4];
            acc = vmax4(acc, vmax4(a0, b0));
        }
    }
    if (r < r1) {   // last odd row
        const vf4* rp0 = fm4 + (size_t)r * rowstride + f4;
        int c = c0;
        for (; c + 1 < c1; c += 2) {
            vf4 a0 = rp0[(size_t)c * FC4];
            vf4 a1 = rp0[(size_t)(c + 1) * FC4];
            acc = vmax4(acc, vmax4(a0, a1));
        }
        if (c < c1) {
            acc = vmax4(acc, rp0[(size_t)c * FC4]);
        }
    }

    vf4* o = reinterpret_cast<vf4*>(out) + (size_t)gid * FC4 + f4;
    __builtin_nontemporal_store(acc, o);
}

extern "C" void kernel_launch(void* const* d_in, const int* in_sizes, int n_in,
                              void* d_out, int out_size, void* d_ws, size_t ws_size,
                              hipStream_t stream) {
    const float* features = (const float*)d_in[0];  // [1,50,50,1024]
    const float* rois     = (const float*)d_in[1];  // [N,4]
    float* out            = (float*)d_out;          // [N,7,7,1024]
    const int N = in_sizes[1] / 4;

    const int nbins = N * POOL * POOL;              // 14700
    // linear grid: block b -> chunk b&3 (XCD-pinned), bins (b>>2)*4 + wave
    dim3 grid(((nbins + 3) / 4) * CHUNKS);
    dim3 block(256);
    roipool_kernel<<<grid, block, 0, stream>>>(features, rois, out, nbins);
}